// Round 7
// baseline (212.342 us; speedup 1.0000x reference)
//
#include <hip/hip_runtime.h>
#include <hip/hip_bf16.h>
#include <hip/hip_cooperative_groups.h>
#include <math.h>

// ---------------------------------------------------------------------------
// BernNet: out = log_softmax( bern_prop( relu(x@W1+b1)@W2+b2 ) )
// bern_prop in monomial basis: out = sum_j a_j A^j v0 (10 matvecs, not 65);
// trailing-zero fast path: all graph work in ONE cooperative kernel that
// returns immediately when a_j==0 for j>=1 (log_softmax fused into MLP).
// MLP: barrier-free phase-1 K-loop — MFMA A/B fragments loaded DIRECTLY from
// global to VGPRs (x per-lane 32B; W1 pre-arranged fragment-linear, L2-hot).
// h1 exchanged through a 32KB conflict-free LDS image (single barrier),
// phase-2 h1@W2 with split hi/lo bf16 W2.
// ---------------------------------------------------------------------------

#define KORD 10

namespace cg = cooperative_groups;

typedef __attribute__((ext_vector_type(8))) short bf16x8;
typedef __attribute__((ext_vector_type(4))) float f32x4;

static __device__ __forceinline__ ushort f2bf(float f) {   // RNE
    unsigned u = __float_as_uint(f);
    unsigned r = (u + 0x7fffu + ((u >> 16) & 1u)) >> 16;
    return (ushort)r;
}
static __device__ __forceinline__ float bf2f(ushort h) {
    return __uint_as_float(((unsigned)h) << 16);
}
static __device__ __forceinline__ uint pack2(float a, float b) {
    return (uint)f2bf(a) | ((uint)f2bf(b) << 16);
}
static __device__ __forceinline__ bf16x8 mk8(uint a, uint b, uint c, uint d) {
    union { uint4 u; bf16x8 v; } x;
    x.u = make_uint4(a, b, c, d);
    return x.v;
}

// ---- one-time setup: monomial coeffs + weight conversion -------------------
// W1 -> fragment-linear bf16: idx = kt*8192 + col*32 + lg*8 + j  (k=kt*32+lg*8+j)
// W2 -> hi/lo bf16:           idx = ks*2048 + col*32 + lg*8 + j  (k=ks*32+lg*8+j)
__global__ void prep_all(const float* __restrict__ temp,
                         const float* __restrict__ W1, const float* __restrict__ W2,
                         float* __restrict__ acoef, int* __restrict__ flags,
                         ushort* __restrict__ w1b,
                         ushort* __restrict__ w2h, ushort* __restrict__ w2l)
{
    int tid = blockIdx.x * 256 + threadIdx.x;
    if (tid == 0) {
        int C[KORD + 1][KORD + 1];
        for (int n = 0; n <= KORD; ++n) {
            for (int k = 0; k <= KORD; ++k) C[n][k] = 0;
            C[n][0] = 1;
            for (int k = 1; k <= n; ++k)
                C[n][k] = C[n - 1][k - 1] + ((k <= n - 1) ? C[n - 1][k] : 0);
        }
        float a[KORD + 1];
        for (int j = 0; j <= KORD; ++j) a[j] = 0.f;
        for (int m = 0; m <= KORD; ++m) {
            float tm = temp[m];
            tm = tm > 0.f ? tm : 0.f;
            float cm = (float)C[KORD][m] / 1024.0f;
            for (int p = 0; p <= m; ++p)
                for (int q = 0; q <= KORD - m; ++q) {
                    int Mij = ((p & 1) ? -1 : 1) * C[m][p] * C[KORD - m][q];
                    a[p + q] += cm * tm * (float)Mij;
                }
        }
        for (int j = 0; j <= KORD; ++j) acoef[j] = a[j];
        int any = 0;
        for (int j = KORD; j >= 0; --j) {
            if (a[j] != 0.f) any = 1;
            flags[j] = any;
        }
    }
    if (tid < 512 * 256) {
        int j = tid & 7, lg = (tid >> 3) & 3, col = (tid >> 5) & 255, kt = tid >> 13;
        int k = kt * 32 + lg * 8 + j;
        w1b[tid] = f2bf(W1[k * 256 + col]);
    } else if (tid < 512 * 256 + 256 * 64) {
        int t2 = tid - 512 * 256;
        int j = t2 & 7, lg = (t2 >> 3) & 3, col = (t2 >> 5) & 63, ks = t2 >> 11;
        int k = ks * 32 + lg * 8 + j;
        float v = W2[k * 64 + col];
        ushort hi = f2bf(v);
        ushort lo = f2bf(v - bf2f(hi));
        w2h[t2] = hi; w2l[t2] = lo;
    }
}

// ---- fused MLP: v0 = relu(x@W1+b1)@W2+b2 ; out = a0*v0 (or lsm(v0)) -------
// 512 thr / 8 waves; tile 64 rows x 256 cols.
// Phase 1: wave (wm=wid>>1, wn=wid&1) computes rows wm*16..+15 x cols
//   wn*128..+127; A (x) and B (W1) fragments loaded directly from global.
// Exchange: h1 bf16 image in 32KB LDS (frag-linear), ONE barrier.
// Phase 2: waves 0..3 (rg=wid>>1... here wid<4: rg=wid) 16 rows x 64 cols.
__global__ __launch_bounds__(512, 4) void mlp_kernel(
    const float* __restrict__ x,
    const ushort* __restrict__ w1b,
    const ushort* __restrict__ w2h, const ushort* __restrict__ w2l,
    const float* __restrict__ b1, const float* __restrict__ b2,
    float* __restrict__ v0, float* __restrict__ out,
    const float* __restrict__ acoef, const int* __restrict__ flags, int N)
{
    __shared__ __align__(16) ushort h1l[64 * 256];      // 32KB frag-linear image

    const int t    = threadIdx.x;
    const int lane = t & 63;
    const int wid  = t >> 6;        // 0..7
    const int wm   = wid >> 1;      // 0..3 row-group (16 rows)
    const int wn   = wid & 1;       // 0..1 col-half (128 cols)
    const int l15  = lane & 15;
    const int lg   = lane >> 4;
    const int row0 = blockIdx.x * 64;

    // ---- phase 1: acc[nf] over cols wn*128+nf*16+l15, rows wm*16+l15 ----
    int grow = row0 + wm * 16 + l15;
    if (grow > N - 1) grow = N - 1;                     // clamp (no OOB)
    const float* xp = x + (size_t)grow * 512 + lg * 8;
    const ushort* bp = w1b + (wn * 128 + l15) * 32 + lg * 8;

    f32x4 acc[8];
#pragma unroll
    for (int i = 0; i < 8; ++i) acc[i] = (f32x4)0.f;

    float4 a0 = *(const float4*)(xp);
    float4 a1 = *(const float4*)(xp + 4);
#pragma unroll 2
    for (int kt = 0; kt < 16; ++kt) {
        int ktx = kt + 1; if (ktx > 15) ktx = 15;       // next-x prefetch
        float4 n0 = *(const float4*)(xp + ktx * 32);
        float4 n1 = *(const float4*)(xp + ktx * 32 + 4);
        bf16x8 A = mk8(pack2(a0.x, a0.y), pack2(a0.z, a0.w),
                       pack2(a1.x, a1.y), pack2(a1.z, a1.w));
        const ushort* bkt = bp + kt * 8192;
#pragma unroll
        for (int nf = 0; nf < 8; ++nf) {
            bf16x8 B = *(const bf16x8*)(bkt + nf * 512);
            acc[nf] = __builtin_amdgcn_mfma_f32_16x16x32_bf16(A, B, acc[nf], 0, 0, 0);
        }
        a0 = n0; a1 = n1;
    }

    // ---- h1 = relu(acc+b1) -> bf16 -> LDS frag-linear image ----
    // element (lrow, col) -> h1l[((ks*4+rg)*64 + (lrow&15)*4 + lgw)*8 + j]
    //   ks=col>>5, rg=lrow>>4, lgw=(col>>3)&3, j=col&7
#pragma unroll
    for (int nf = 0; nf < 8; ++nf) {
        int col = wn * 128 + nf * 16 + l15;
        float bb = b1[col];
        int ks = col >> 5, lgw = (col >> 3) & 3, j = col & 7;
#pragma unroll
        for (int r = 0; r < 4; ++r) {
            float v = fmaxf(acc[nf][r] + bb, 0.f);
            int lrow = lg * 4 + r;                      // row within group wm
            h1l[((ks * 4 + wm) * 64 + lrow * 4 + lgw) * 8 + j] = f2bf(v);
        }
    }
    __syncthreads();

    if (wid >= 4) return;                               // no barriers below

    // ---- phase 2: wave wid -> rows wid*16..+15, all 64 cols, K=256 ----
    f32x4 acc2[4];
#pragma unroll
    for (int i = 0; i < 4; ++i) acc2[i] = (f32x4)0.f;
#pragma unroll
    for (int ks = 0; ks < 8; ++ks) {
        bf16x8 A = *(const bf16x8*)&h1l[((ks * 4 + wid) * 64 + l15 * 4 + lg) * 8];
#pragma unroll
        for (int nf = 0; nf < 4; ++nf) {
            size_t bo = (size_t)ks * 2048 + (nf * 16 + l15) * 32 + (lg << 3);
            bf16x8 Bh = *(const bf16x8*)(w2h + bo);
            bf16x8 Bl = *(const bf16x8*)(w2l + bo);
            acc2[nf] = __builtin_amdgcn_mfma_f32_16x16x32_bf16(A, Bh, acc2[nf], 0, 0, 0);
            acc2[nf] = __builtin_amdgcn_mfma_f32_16x16x32_bf16(A, Bl, acc2[nf], 0, 0, 0);
        }
    }

    // ---- epilogue ----
    int flag1 = flags[1];
    float a0c = acoef[0];
    float z[4][4];
#pragma unroll
    for (int nf = 0; nf < 4; ++nf) {
        float bb = b2[nf * 16 + l15];
#pragma unroll
        for (int r = 0; r < 4; ++r) z[nf][r] = acc2[nf][r] + bb;
    }
    if (!flag1) {
        // fused log_softmax: the 16 l15-lanes of this lg group share 4 rows
#pragma unroll
        for (int r = 0; r < 4; ++r) {
            int row = row0 + wid * 16 + lg * 4 + r;
            float mx = fmaxf(fmaxf(z[0][r], z[1][r]), fmaxf(z[2][r], z[3][r]));
#pragma unroll
            for (int off = 1; off < 16; off <<= 1) mx = fmaxf(mx, __shfl_xor(mx, off, 64));
            float s = expf(z[0][r] - mx) + expf(z[1][r] - mx)
                    + expf(z[2][r] - mx) + expf(z[3][r] - mx);
#pragma unroll
            for (int off = 1; off < 16; off <<= 1) s += __shfl_xor(s, off, 64);
            float lns = logf(s);
            if (row < N) {
#pragma unroll
                for (int nf = 0; nf < 4; ++nf)
                    out[(size_t)row * 64 + nf * 16 + l15] = z[nf][r] - mx - lns;
            }
        }
    } else {
#pragma unroll
        for (int nf = 0; nf < 4; ++nf) {
            int col = nf * 16 + l15;
#pragma unroll
            for (int r = 0; r < 4; ++r) {
                int row = row0 + wid * 16 + lg * 4 + r;
                if (row < N) {
                    size_t o = (size_t)row * 64 + col;
                    v0[o] = z[nf][r];
                    out[o] = a0c * z[nf][r];
                }
            }
        }
    }
}

// ---- all graph work in one cooperative kernel (active path only) ----------
__global__ __launch_bounds__(256) void graph_coop(
    const int* __restrict__ src, const int* __restrict__ dst, int E, int N,
    int* __restrict__ degs, int* __restrict__ degd, int* __restrict__ cursor,
    int* __restrict__ rowp, int* __restrict__ csrs, float* __restrict__ csrw,
    float* __restrict__ v0, float* __restrict__ v1, float* __restrict__ out,
    const float* __restrict__ acoef, const int* __restrict__ flags)
{
    __shared__ int sums[256];
    if (!flags[1]) return;                  // uniform early-out: no syncs occur
    cg::grid_group grid = cg::this_grid();
    int gtid = blockIdx.x * 256 + threadIdx.x;
    int gstr = gridDim.x * 256;

    // phase 0: zero
    for (int i = gtid; i < N; i += gstr) { degs[i] = 0; degd[i] = 0; cursor[i] = 0; }
    grid.sync();
    // phase 1: degree count
    for (int e = gtid; e < E; e += gstr) {
        atomicAdd(&degs[src[e]], 1);
        atomicAdd(&degd[dst[e]], 1);
    }
    grid.sync();
    // phase 2: exclusive prefix over degd -> rowp (block 0)
    if (blockIdx.x == 0) {
        int tid = threadIdx.x;
        int chunk = (N + 255) / 256;
        int s0 = tid * chunk;
        int s1 = s0 + chunk; if (s1 > N) s1 = N; if (s0 > N) s0 = N;
        int s = 0;
        for (int i = s0; i < s1; ++i) s += degd[i];
        sums[tid] = s;
        __syncthreads();
        for (int off = 1; off < 256; off <<= 1) {
            int v = (tid >= off) ? sums[tid - off] : 0;
            __syncthreads();
            sums[tid] += v;
            __syncthreads();
        }
        int run = sums[tid] - s;
        for (int i = s0; i < s1; ++i) { rowp[i] = run; run += degd[i]; }
        if (tid == 255) rowp[N] = sums[255];
    }
    grid.sync();
    // phase 3: CSR fill (sym-norm weight from out-degree, as in reference)
    for (int e = gtid; e < E; e += gstr) {
        int s = src[e], d = dst[e];
        int dgs = degs[s], dgd = degs[d];
        float ws_ = (dgs > 0 ? rsqrtf((float)dgs) : 0.f)
                  * (dgd > 0 ? rsqrtf((float)dgd) : 0.f);
        int slot = rowp[d] + atomicAdd(&cursor[d], 1);
        csrs[slot] = s;
        csrw[slot] = ws_;
    }
    grid.sync();
    // phase 4: out += a_j * A^j v0, j = 1..K
    const float* va = v0;
    float* vb = v1;
    int lane = threadIdx.x & 63;
    int grpbase = lane & 48;
    for (int j = 1; j <= KORD; ++j) {
        if (!flags[j]) break;               // uniform
        float aj = acoef[j];
        for (int idx = gtid; idx < N * 16; idx += gstr) {
            int n = idx >> 4;
            int q = idx & 15;
            int beg = rowp[n], end = rowp[n + 1];
            float4 acc = make_float4(0.f, 0.f, 0.f, 0.f);
            for (int base = beg; base < end; base += 16) {
                int s = 0; float wvv = 0.f;
                int ii = base + q;
                if (ii < end) { s = csrs[ii]; wvv = csrw[ii]; }
                int m = end - base; if (m > 16) m = 16;
                for (int u = 0; u < m; ++u) {
                    int ss = __shfl(s, grpbase + u, 64);
                    float ww = __shfl(wvv, grpbase + u, 64);
                    float4 vv = *(const float4*)(va + ((long)ss << 6) + (q << 2));
                    acc.x += ww * vv.x; acc.y += ww * vv.y;
                    acc.z += ww * vv.z; acc.w += ww * vv.w;
                }
            }
            long o = ((long)n << 6) + (q << 2);
            *(float4*)(vb + o) = acc;
            float4 ov = *(const float4*)(out + o);
            ov.x += aj * acc.x; ov.y += aj * acc.y;
            ov.z += aj * acc.z; ov.w += aj * acc.w;
            *(float4*)(out + o) = ov;
        }
        grid.sync();
        float* tsw = vb; vb = (float*)va; va = tsw;
    }
    // phase 5: log_softmax
    for (int idx = gtid; idx < N * 64; idx += gstr) {
        int n = idx >> 6;
        int c = idx & 63;
        float v = out[(long)n * 64 + c];
        float mx = v;
#pragma unroll
        for (int off = 32; off; off >>= 1) mx = fmaxf(mx, __shfl_xor(mx, off, 64));
        float e = expf(v - mx);
        float s = e;
#pragma unroll
        for (int off = 32; off; off >>= 1) s += __shfl_xor(s, off, 64);
        out[(long)n * 64 + c] = v - mx - logf(s);
    }
}

extern "C" void kernel_launch(void* const* d_in, const int* in_sizes, int n_in,
                              void* d_out, int out_size, void* d_ws, size_t ws_size,
                              hipStream_t stream)
{
    const float* x    = (const float*)d_in[0];
    const int*   ei   = (const int*)d_in[1];
    const float* W1   = (const float*)d_in[2];
    const float* b1   = (const float*)d_in[3];
    const float* W2   = (const float*)d_in[4];
    const float* b2   = (const float*)d_in[5];
    const float* temp = (const float*)d_in[6];

    int N = in_sizes[0] / 512;
    int E = in_sizes[1] / 2;
    const int* src = ei;
    const int* dst = ei + E;
    float* out = (float*)d_out;

    char* w = (char*)d_ws;
    auto alloc = [&](size_t bytes) {
        char* p = w;
        w += (bytes + 255) & ~(size_t)255;
        return p;
    };
    float* acoef  = (float*)alloc(64);
    int*   flags  = (int*)alloc(64);
    int*   degs   = (int*)alloc((size_t)N * 4);
    int*   degd   = (int*)alloc((size_t)N * 4);
    int*   cursor = (int*)alloc((size_t)N * 4);
    int*   rowp   = (int*)alloc((size_t)(N + 1) * 4);
    int*   csrs   = (int*)alloc((size_t)E * 4);
    float* csrw   = (float*)alloc((size_t)E * 4);
    ushort* w1b   = (ushort*)alloc(512 * 256 * 2);
    ushort* w2h   = (ushort*)alloc(256 * 64 * 2);
    ushort* w2l   = (ushort*)alloc(256 * 64 * 2);
    float* v0     = (float*)alloc((size_t)N * 64 * 4);
    float* v1     = (float*)alloc((size_t)N * 64 * 4);

    prep_all<<<576, 256, 0, stream>>>(temp, W1, W2, acoef, flags, w1b, w2h, w2l);

    int ntiles = (N + 63) / 64;
    mlp_kernel<<<ntiles, 512, 0, stream>>>(x, w1b, w2h, w2l, b1, b2, v0, out,
                                           acoef, flags, N);

    int Ei = E, Ni = N;
    void* cargs[] = {
        (void*)&src, (void*)&dst, (void*)&Ei, (void*)&Ni,
        (void*)&degs, (void*)&degd, (void*)&cursor, (void*)&rowp,
        (void*)&csrs, (void*)&csrw, (void*)&v0, (void*)&v1, (void*)&out,
        (void*)&acoef, (void*)&flags
    };
    hipLaunchCooperativeKernel((void*)graph_coop, dim3(1024), dim3(256),
                               cargs, 0, stream);
}

// Round 8
// 125.964 us; speedup vs baseline: 1.6857x; 1.6857x over previous
//
#include <hip/hip_runtime.h>
#include <hip/hip_bf16.h>
#include <hip/hip_cooperative_groups.h>
#include <math.h>

// ---------------------------------------------------------------------------
// BernNet: out = log_softmax( bern_prop( relu(x@W1+b1)@W2+b2 ) )
// bern_prop in monomial basis (10 matvecs, not 65); trailing-zero fast path:
// graph work in ONE cooperative kernel that exits when a_j==0 for j>=1
// (log_softmax then fused into the MLP epilogue).
// MLP phase-1 K-loop: counted-vmcnt pipeline (T3/T4) — W1 triple-buffered in
// LDS via global_load_lds, x direct global->VGPR via inline-asm loads, all
// VMEM in 4-op groups pinned by sched_barrier(0); raw s_barrier pairs;
// s_waitcnt vmcnt(8) keeps 2 iterations of prefetch in flight (never 0 in
// the main loop). h1 kept in LDS; phase-2 h1@W2 with split hi/lo bf16 W2.
// ---------------------------------------------------------------------------

#define KORD 10

namespace cg = cooperative_groups;

typedef __attribute__((ext_vector_type(8))) short bf16x8;
typedef __attribute__((ext_vector_type(4))) float f32x4;

typedef __attribute__((address_space(1))) const unsigned int* gas_t;
typedef __attribute__((address_space(3))) unsigned int* las_t;

static __device__ __forceinline__ void gll16(const void* g, void* l) {
    // per-lane global addr g; wave-uniform LDS base l; writes l + lane*16
    __builtin_amdgcn_global_load_lds((gas_t)g, (las_t)l, 16, 0, 0);
}

static __device__ __forceinline__ ushort f2bf(float f) {   // RNE
    unsigned u = __float_as_uint(f);
    unsigned r = (u + 0x7fffu + ((u >> 16) & 1u)) >> 16;
    return (ushort)r;
}
static __device__ __forceinline__ float bf2f(ushort h) {
    return __uint_as_float(((unsigned)h) << 16);
}
static __device__ __forceinline__ uint pack2(float a, float b) {
    return (uint)f2bf(a) | ((uint)f2bf(b) << 16);
}
static __device__ __forceinline__ bf16x8 mk8(uint a, uint b, uint c, uint d) {
    union { uint4 u; bf16x8 v; } x;
    x.u = make_uint4(a, b, c, d);
    return x.v;
}

// two 16B global loads (addr, addr+16) as inline asm so they sit in OUR vmcnt
// queue position (compiler-invisible results; completion enforced by the
// counted s_waitcnt in the pipeline).
#define GLOAD2(d0, d1, p)                                                      \
    asm volatile("global_load_dwordx4 %0, %2, off\n\t"                         \
                 "global_load_dwordx4 %1, %2, off offset:16"                   \
                 : "=&v"(d0), "=&v"(d1)                                        \
                 : "v"((unsigned long long)(size_t)(p))                        \
                 : "memory")

#define WAITVM(n) asm volatile("s_waitcnt vmcnt(" #n ")" ::: "memory")
#define SB0() __builtin_amdgcn_sched_barrier(0)

// ---- one-time setup: monomial coeffs + weight conversion -------------------
// W1 -> fragment-linear bf16: idx = kt*8192 + col*32 + lg*8 + j  (k=kt*32+lg*8+j)
// W2 -> hi/lo bf16:           idx = ks*2048 + col*32 + lg*8 + j  (k=ks*32+lg*8+j)
__global__ void prep_all(const float* __restrict__ temp,
                         const float* __restrict__ W1, const float* __restrict__ W2,
                         float* __restrict__ acoef, int* __restrict__ flags,
                         ushort* __restrict__ w1b,
                         ushort* __restrict__ w2h, ushort* __restrict__ w2l)
{
    int tid = blockIdx.x * 256 + threadIdx.x;
    if (tid == 0) {
        int C[KORD + 1][KORD + 1];
        for (int n = 0; n <= KORD; ++n) {
            for (int k = 0; k <= KORD; ++k) C[n][k] = 0;
            C[n][0] = 1;
            for (int k = 1; k <= n; ++k)
                C[n][k] = C[n - 1][k - 1] + ((k <= n - 1) ? C[n - 1][k] : 0);
        }
        float a[KORD + 1];
        for (int j = 0; j <= KORD; ++j) a[j] = 0.f;
        for (int m = 0; m <= KORD; ++m) {
            float tm = temp[m];
            tm = tm > 0.f ? tm : 0.f;
            float cm = (float)C[KORD][m] / 1024.0f;
            for (int p = 0; p <= m; ++p)
                for (int q = 0; q <= KORD - m; ++q) {
                    int Mij = ((p & 1) ? -1 : 1) * C[m][p] * C[KORD - m][q];
                    a[p + q] += cm * tm * (float)Mij;
                }
        }
        for (int j = 0; j <= KORD; ++j) acoef[j] = a[j];
        int any = 0;
        for (int j = KORD; j >= 0; --j) {
            if (a[j] != 0.f) any = 1;
            flags[j] = any;
        }
    }
    if (tid < 512 * 256) {
        int j = tid & 7, lg = (tid >> 3) & 3, col = (tid >> 5) & 255, kt = tid >> 13;
        int k = kt * 32 + lg * 8 + j;
        w1b[tid] = f2bf(W1[k * 256 + col]);
    } else if (tid < 512 * 256 + 256 * 64) {
        int t2 = tid - 512 * 256;
        int j = t2 & 7, lg = (t2 >> 3) & 3, col = (t2 >> 5) & 63, ks = t2 >> 11;
        int k = ks * 32 + lg * 8 + j;
        float v = W2[k * 64 + col];
        ushort hi = f2bf(v);
        ushort lo = f2bf(v - bf2f(hi));
        w2h[t2] = hi; w2l[t2] = lo;
    }
}

// ---- fused MLP ------------------------------------------------------------
// 512 thr / 8 waves; tile 64 rows x 256 cols. Phase-1: wave (wm=wid>>1 rows
// wm*16..+15, wn=wid&1 cols wn*128..+127); x direct-from-global A-frags,
// W1 from 3-deep LDS ring staged 2 iterations ahead. One 4-op VMEM group
// per iteration; vmcnt(8) steady state.
__global__ __launch_bounds__(512, 4) void mlp_kernel(
    const float* __restrict__ x,
    const ushort* __restrict__ w1b,
    const ushort* __restrict__ w2h, const ushort* __restrict__ w2l,
    const float* __restrict__ b1, const float* __restrict__ b2,
    float* __restrict__ v0, float* __restrict__ out,
    const float* __restrict__ acoef, const int* __restrict__ flags, int N)
{
    __shared__ __align__(16) char sm[49152];   // 3 x 16KB W1 ring; h1 image reuses [0:32K)

    const int t    = threadIdx.x;
    const int lane = t & 63;
    const int wid  = t >> 6;        // 0..7
    const int wm   = wid >> 1;      // 0..3 row-group (16 rows)
    const int wn   = wid & 1;       // 0..1 col-half (128 cols)
    const int l15  = lane & 15;
    const int lg   = lane >> 4;
    const int row0 = blockIdx.x * 64;

    int grow = row0 + wm * 16 + l15;
    if (grow > N - 1) grow = N - 1;                     // clamp (no OOB)
    const float* xp = x + (size_t)grow * 512 + lg * 8;
    const char* w1g = (const char*)w1b;
    const int stg = wid * 2048;                         // this wave's 2KB slice

    f32x4 acc[8];
#pragma unroll
    for (int i = 0; i < 8; ++i) acc[i] = (f32x4)0.f;

    f32x4 xs0[3], xs1[3];

    // ---- prologue: two pinned 4-op groups ----
    SB0();
    gll16(w1g + 0 * 16384 + stg + lane * 16,        sm + 0 * 16384 + stg);
    gll16(w1g + 0 * 16384 + stg + 1024 + lane * 16, sm + 0 * 16384 + stg + 1024);
    GLOAD2(xs0[0], xs1[0], xp + 0 * 32);
    SB0();
    gll16(w1g + 1 * 16384 + stg + lane * 16,        sm + 1 * 16384 + stg);
    gll16(w1g + 1 * 16384 + stg + 1024 + lane * 16, sm + 1 * 16384 + stg + 1024);
    GLOAD2(xs0[1], xs1[1], xp + 1 * 32);
    SB0();

#define P1_ITER(J, CNT)                                                         \
    {                                                                           \
        SB0();                                                                  \
        __builtin_amdgcn_s_barrier();   /* release: prior reads of buf done */  \
        SB0();                                                                  \
        if ((J) + 2 <= 15) {                                                    \
            const char* gsrc = w1g + ((J) + 2) * 16384 + stg;                   \
            char* ldst = sm + (((J) + 2) % 3) * 16384 + stg;                    \
            gll16(gsrc + lane * 16,        ldst);                               \
            gll16(gsrc + 1024 + lane * 16, ldst + 1024);                        \
            GLOAD2(xs0[((J) + 2) % 3], xs1[((J) + 2) % 3], xp + ((J) + 2) * 32);\
        }                                                                       \
        SB0();                                                                  \
        WAITVM(CNT);                                                            \
        SB0();                                                                  \
        __builtin_amdgcn_s_barrier();   /* acquire: buf[J] landed everywhere */ \
        SB0();                                                                  \
        {                                                                       \
            f32x4 a0 = xs0[(J) % 3], a1 = xs1[(J) % 3];                         \
            bf16x8 A = mk8(pack2(a0.x, a0.y), pack2(a0.z, a0.w),                \
                           pack2(a1.x, a1.y), pack2(a1.z, a1.w));               \
            const char* bufb = sm + ((J) % 3) * 16384;                          \
            _Pragma("unroll")                                                   \
            for (int nf = 0; nf < 8; ++nf) {                                    \
                bf16x8 B = *(const bf16x8*)(bufb +                              \
                            (wn * 128 + nf * 16 + l15) * 64 + lg * 16);         \
                acc[nf] = __builtin_amdgcn_mfma_f32_16x16x32_bf16(A, B,         \
                                                          acc[nf], 0, 0, 0);    \
            }                                                                   \
        }                                                                       \
    }

    P1_ITER(0, 8)  P1_ITER(1, 8)  P1_ITER(2, 8)  P1_ITER(3, 8)
    P1_ITER(4, 8)  P1_ITER(5, 8)  P1_ITER(6, 8)  P1_ITER(7, 8)
    P1_ITER(8, 8)  P1_ITER(9, 8)  P1_ITER(10, 8) P1_ITER(11, 8)
    P1_ITER(12, 8) P1_ITER(13, 8) P1_ITER(14, 4) P1_ITER(15, 0)
#undef P1_ITER

    __syncthreads();                                    // ring dead; reuse as h1 image

    // ---- h1 = relu(acc+b1) -> bf16 -> LDS frag-linear image [0:32K) ----
    ushort* h1l = (ushort*)sm;
#pragma unroll
    for (int nf = 0; nf < 8; ++nf) {
        int col = wn * 128 + nf * 16 + l15;
        float bb = b1[col];
        int ks = col >> 5, lgw = (col >> 3) & 3, j = col & 7;
#pragma unroll
        for (int r = 0; r < 4; ++r) {
            float v = fmaxf(acc[nf][r] + bb, 0.f);
            int lrow = lg * 4 + r;
            h1l[((ks * 4 + wm) * 64 + lrow * 4 + lgw) * 8 + j] = f2bf(v);
        }
    }
    __syncthreads();

    if (wid >= 4) return;                               // no barriers below

    // ---- phase 2: wave wid -> rows wid*16..+15, all 64 cols, K=256 ----
    f32x4 acc2[4];
#pragma unroll
    for (int i = 0; i < 4; ++i) acc2[i] = (f32x4)0.f;
#pragma unroll
    for (int ks = 0; ks < 8; ++ks) {
        bf16x8 A = *(const bf16x8*)&h1l[((ks * 4 + wid) * 64 + l15 * 4 + lg) * 8];
#pragma unroll
        for (int nf = 0; nf < 4; ++nf) {
            size_t bo = (size_t)ks * 2048 + (nf * 16 + l15) * 32 + (lg << 3);
            bf16x8 Bh = *(const bf16x8*)(w2h + bo);
            bf16x8 Bl = *(const bf16x8*)(w2l + bo);
            acc2[nf] = __builtin_amdgcn_mfma_f32_16x16x32_bf16(A, Bh, acc2[nf], 0, 0, 0);
            acc2[nf] = __builtin_amdgcn_mfma_f32_16x16x32_bf16(A, Bl, acc2[nf], 0, 0, 0);
        }
    }

    // ---- epilogue ----
    int flag1 = flags[1];
    float a0c = acoef[0];
    float z[4][4];
#pragma unroll
    for (int nf = 0; nf < 4; ++nf) {
        float bb = b2[nf * 16 + l15];
#pragma unroll
        for (int r = 0; r < 4; ++r) z[nf][r] = acc2[nf][r] + bb;
    }
    if (!flag1) {
        // fused log_softmax: the 16 l15-lanes of this lg group share 4 rows
#pragma unroll
        for (int r = 0; r < 4; ++r) {
            int row = row0 + wid * 16 + lg * 4 + r;
            float mx = fmaxf(fmaxf(z[0][r], z[1][r]), fmaxf(z[2][r], z[3][r]));
#pragma unroll
            for (int off = 1; off < 16; off <<= 1) mx = fmaxf(mx, __shfl_xor(mx, off, 64));
            float s = expf(z[0][r] - mx) + expf(z[1][r] - mx)
                    + expf(z[2][r] - mx) + expf(z[3][r] - mx);
#pragma unroll
            for (int off = 1; off < 16; off <<= 1) s += __shfl_xor(s, off, 64);
            float lns = logf(s);
            if (row < N) {
#pragma unroll
                for (int nf = 0; nf < 4; ++nf)
                    out[(size_t)row * 64 + nf * 16 + l15] = z[nf][r] - mx - lns;
            }
        }
    } else {
#pragma unroll
        for (int nf = 0; nf < 4; ++nf) {
            int col = nf * 16 + l15;
#pragma unroll
            for (int r = 0; r < 4; ++r) {
                int row = row0 + wid * 16 + lg * 4 + r;
                if (row < N) {
                    size_t o = (size_t)row * 64 + col;
                    v0[o] = z[nf][r];
                    out[o] = a0c * z[nf][r];
                }
            }
        }
    }
}

// ---- all graph work in one cooperative kernel (active path only) ----------
__global__ __launch_bounds__(256) void graph_coop(
    const int* __restrict__ src, const int* __restrict__ dst, int E, int N,
    int* __restrict__ degs, int* __restrict__ degd, int* __restrict__ cursor,
    int* __restrict__ rowp, int* __restrict__ csrs, float* __restrict__ csrw,
    float* __restrict__ v0, float* __restrict__ v1, float* __restrict__ out,
    const float* __restrict__ acoef, const int* __restrict__ flags)
{
    __shared__ int sums[256];
    if (!flags[1]) return;                  // uniform early-out: no syncs occur
    cg::grid_group grid = cg::this_grid();
    int gtid = blockIdx.x * 256 + threadIdx.x;
    int gstr = gridDim.x * 256;

    for (int i = gtid; i < N; i += gstr) { degs[i] = 0; degd[i] = 0; cursor[i] = 0; }
    grid.sync();
    for (int e = gtid; e < E; e += gstr) {
        atomicAdd(&degs[src[e]], 1);
        atomicAdd(&degd[dst[e]], 1);
    }
    grid.sync();
    if (blockIdx.x == 0) {
        int tid = threadIdx.x;
        int chunk = (N + 255) / 256;
        int s0 = tid * chunk;
        int s1 = s0 + chunk; if (s1 > N) s1 = N; if (s0 > N) s0 = N;
        int s = 0;
        for (int i = s0; i < s1; ++i) s += degd[i];
        sums[tid] = s;
        __syncthreads();
        for (int off = 1; off < 256; off <<= 1) {
            int v = (tid >= off) ? sums[tid - off] : 0;
            __syncthreads();
            sums[tid] += v;
            __syncthreads();
        }
        int run = sums[tid] - s;
        for (int i = s0; i < s1; ++i) { rowp[i] = run; run += degd[i]; }
        if (tid == 255) rowp[N] = sums[255];
    }
    grid.sync();
    for (int e = gtid; e < E; e += gstr) {
        int s = src[e], d = dst[e];
        int dgs = degs[s], dgd = degs[d];
        float ws_ = (dgs > 0 ? rsqrtf((float)dgs) : 0.f)
                  * (dgd > 0 ? rsqrtf((float)dgd) : 0.f);
        int slot = rowp[d] + atomicAdd(&cursor[d], 1);
        csrs[slot] = s;
        csrw[slot] = ws_;
    }
    grid.sync();
    const float* va = v0;
    float* vb = v1;
    int lane = threadIdx.x & 63;
    int grpbase = lane & 48;
    for (int j = 1; j <= KORD; ++j) {
        if (!flags[j]) break;               // uniform
        float aj = acoef[j];
        for (int idx = gtid; idx < N * 16; idx += gstr) {
            int n = idx >> 4;
            int q = idx & 15;
            int beg = rowp[n], end = rowp[n + 1];
            float4 acc = make_float4(0.f, 0.f, 0.f, 0.f);
            for (int base = beg; base < end; base += 16) {
                int s = 0; float wvv = 0.f;
                int ii = base + q;
                if (ii < end) { s = csrs[ii]; wvv = csrw[ii]; }
                int m = end - base; if (m > 16) m = 16;
                for (int u = 0; u < m; ++u) {
                    int ss = __shfl(s, grpbase + u, 64);
                    float ww = __shfl(wvv, grpbase + u, 64);
                    float4 vv = *(const float4*)(va + ((long)ss << 6) + (q << 2));
                    acc.x += ww * vv.x; acc.y += ww * vv.y;
                    acc.z += ww * vv.z; acc.w += ww * vv.w;
                }
            }
            long o = ((long)n << 6) + (q << 2);
            *(float4*)(vb + o) = acc;
            float4 ov = *(const float4*)(out + o);
            ov.x += aj * acc.x; ov.y += aj * acc.y;
            ov.z += aj * acc.z; ov.w += aj * acc.w;
            *(float4*)(out + o) = ov;
        }
        grid.sync();
        float* tsw = vb; vb = (float*)va; va = tsw;
    }
    for (int idx = gtid; idx < N * 64; idx += gstr) {
        int n = idx >> 6;
        int c = idx & 63;
        float v = out[(long)n * 64 + c];
        float mx = v;
#pragma unroll
        for (int off = 32; off; off >>= 1) mx = fmaxf(mx, __shfl_xor(mx, off, 64));
        float e = expf(v - mx);
        float s = e;
#pragma unroll
        for (int off = 32; off; off >>= 1) s += __shfl_xor(s, off, 64);
        out[(long)n * 64 + c] = v - mx - logf(s);
    }
}

extern "C" void kernel_launch(void* const* d_in, const int* in_sizes, int n_in,
                              void* d_out, int out_size, void* d_ws, size_t ws_size,
                              hipStream_t stream)
{
    const float* x    = (const float*)d_in[0];
    const int*   ei   = (const int*)d_in[1];
    const float* W1   = (const float*)d_in[2];
    const float* b1   = (const float*)d_in[3];
    const float* W2   = (const float*)d_in[4];
    const float* b2   = (const float*)d_in[5];
    const float* temp = (const float*)d_in[6];

    int N = in_sizes[0] / 512;
    int E = in_sizes[1] / 2;
    const int* src = ei;
    const int* dst = ei + E;
    float* out = (float*)d_out;

    char* w = (char*)d_ws;
    auto alloc = [&](size_t bytes) {
        char* p = w;
        w += (bytes + 255) & ~(size_t)255;
        return p;
    };
    float* acoef  = (float*)alloc(64);
    int*   flags  = (int*)alloc(64);
    int*   degs   = (int*)alloc((size_t)N * 4);
    int*   degd   = (int*)alloc((size_t)N * 4);
    int*   cursor = (int*)alloc((size_t)N * 4);
    int*   rowp   = (int*)alloc((size_t)(N + 1) * 4);
    int*   csrs   = (int*)alloc((size_t)E * 4);
    float* csrw   = (float*)alloc((size_t)E * 4);
    ushort* w1b   = (ushort*)alloc(512 * 256 * 2);
    ushort* w2h   = (ushort*)alloc(256 * 64 * 2);
    ushort* w2l   = (ushort*)alloc(256 * 64 * 2);
    float* v0     = (float*)alloc((size_t)N * 64 * 4);
    float* v1     = (float*)alloc((size_t)N * 64 * 4);

    prep_all<<<576, 256, 0, stream>>>(temp, W1, W2, acoef, flags, w1b, w2h, w2l);

    int ntiles = (N + 63) / 64;
    mlp_kernel<<<ntiles, 512, 0, stream>>>(x, w1b, w2h, w2l, b1, b2, v0, out,
                                           acoef, flags, N);

    int Ei = E, Ni = N;
    void* cargs[] = {
        (void*)&src, (void*)&dst, (void*)&Ei, (void*)&Ni,
        (void*)&degs, (void*)&degd, (void*)&cursor, (void*)&rowp,
        (void*)&csrs, (void*)&csrw, (void*)&v0, (void*)&v1, (void*)&out,
        (void*)&acoef, (void*)&flags
    };
    hipLaunchCooperativeKernel((void*)graph_coop, dim3(1024), dim3(256),
                               cargs, 0, stream);
}

// Round 9
// 121.940 us; speedup vs baseline: 1.7414x; 1.0330x over previous
//
#include <hip/hip_runtime.h>
#include <hip/hip_bf16.h>
#include <hip/hip_cooperative_groups.h>
#include <math.h>

// ---------------------------------------------------------------------------
// BernNet: out = log_softmax( bern_prop( relu(x@W1+b1)@W2+b2 ) )
// bern_prop in monomial basis (10 matvecs, not 65); trailing-zero fast path:
// graph work in ONE cooperative kernel that exits when a_j==0 for j>=1
// (log_softmax then fused into the MLP epilogue).
// MLP: x tile (full K=512) staged ONCE into LDS as bf16 frag-linear image;
// phase-1 K-loop is barrier-free pure dataflow: A via conflict-free
// ds_read_b128, B streamed per-wave from L2-resident fragment-linear w1b
// with depth-1 register double-buffer. Wave = 64 rows x 32 cols (no
// duplicated B reads). h1 kept in LDS; phase-2 h1@W2 with split hi/lo W2.
// ---------------------------------------------------------------------------

#define KORD 10

namespace cg = cooperative_groups;

typedef __attribute__((ext_vector_type(8))) short bf16x8;
typedef __attribute__((ext_vector_type(4))) float f32x4;

static __device__ __forceinline__ ushort f2bf(float f) {   // RNE
    unsigned u = __float_as_uint(f);
    unsigned r = (u + 0x7fffu + ((u >> 16) & 1u)) >> 16;
    return (ushort)r;
}
static __device__ __forceinline__ float bf2f(ushort h) {
    return __uint_as_float(((unsigned)h) << 16);
}
static __device__ __forceinline__ uint pack2(float a, float b) {
    return (uint)f2bf(a) | ((uint)f2bf(b) << 16);
}

// ---- one-time setup: monomial coeffs + weight conversion -------------------
// W1 -> fragment-linear bf16: idx = kt*8192 + col*32 + lg*8 + j  (k=kt*32+lg*8+j)
// W2 -> hi/lo bf16:           idx = ks*2048 + col*32 + lg*8 + j  (k=ks*32+lg*8+j)
__global__ void prep_all(const float* __restrict__ temp,
                         const float* __restrict__ W1, const float* __restrict__ W2,
                         float* __restrict__ acoef, int* __restrict__ flags,
                         ushort* __restrict__ w1b,
                         ushort* __restrict__ w2h, ushort* __restrict__ w2l)
{
    int tid = blockIdx.x * 256 + threadIdx.x;
    if (tid == 0) {
        int C[KORD + 1][KORD + 1];
        for (int n = 0; n <= KORD; ++n) {
            for (int k = 0; k <= KORD; ++k) C[n][k] = 0;
            C[n][0] = 1;
            for (int k = 1; k <= n; ++k)
                C[n][k] = C[n - 1][k - 1] + ((k <= n - 1) ? C[n - 1][k] : 0);
        }
        float a[KORD + 1];
        for (int j = 0; j <= KORD; ++j) a[j] = 0.f;
        for (int m = 0; m <= KORD; ++m) {
            float tm = temp[m];
            tm = tm > 0.f ? tm : 0.f;
            float cm = (float)C[KORD][m] / 1024.0f;
            for (int p = 0; p <= m; ++p)
                for (int q = 0; q <= KORD - m; ++q) {
                    int Mij = ((p & 1) ? -1 : 1) * C[m][p] * C[KORD - m][q];
                    a[p + q] += cm * tm * (float)Mij;
                }
        }
        for (int j = 0; j <= KORD; ++j) acoef[j] = a[j];
        int any = 0;
        for (int j = KORD; j >= 0; --j) {
            if (a[j] != 0.f) any = 1;
            flags[j] = any;
        }
    }
    if (tid < 512 * 256) {
        int j = tid & 7, lg = (tid >> 3) & 3, col = (tid >> 5) & 255, kt = tid >> 13;
        int k = kt * 32 + lg * 8 + j;
        w1b[tid] = f2bf(W1[k * 256 + col]);
    } else if (tid < 512 * 256 + 256 * 64) {
        int t2 = tid - 512 * 256;
        int j = t2 & 7, lg = (t2 >> 3) & 3, col = (t2 >> 5) & 63, ks = t2 >> 11;
        int k = ks * 32 + lg * 8 + j;
        float v = W2[k * 64 + col];
        ushort hi = f2bf(v);
        ushort lo = f2bf(v - bf2f(hi));
        w2h[t2] = hi; w2l[t2] = lo;
    }
}

// ---- fused MLP ------------------------------------------------------------
// 512 thr / 8 waves; tile 64 rows x 256 cols, K=512.
// Phase 1: wave wid owns cols wid*32..+31 (2 col-groups), ALL 64 rows
// (4 row-groups). A from LDS x image; B from global (L2) dbuf'd in regs.
__global__ __launch_bounds__(512, 4) void mlp_kernel(
    const float* __restrict__ x,
    const ushort* __restrict__ w1b,
    const ushort* __restrict__ w2h, const ushort* __restrict__ w2l,
    const float* __restrict__ b1, const float* __restrict__ b2,
    float* __restrict__ v0, float* __restrict__ out,
    const float* __restrict__ acoef, const int* __restrict__ flags, int N)
{
    __shared__ __align__(16) ushort xImg[64 * 512];   // 64KB; h1 reuses [0:16384)

    const int t    = threadIdx.x;
    const int lane = t & 63;
    const int wid  = t >> 6;        // 0..7
    const int l15  = lane & 15;
    const int lg   = lane >> 4;
    const int row0 = blockIdx.x * 64;

    // ---- stage x tile (64 rows x 512 K) -> bf16 frag-linear LDS image ----
    // element (row,k): idx = ((kt*4+g)*64 + (row&15)*4 + (k>>3&3))*8 + (k&7)
    {
        const int srow = t >> 3;                       // 0..63
        const int sc   = t & 7;                        // 64-float chunk
        int gr = row0 + srow; if (gr > N - 1) gr = N - 1;   // clamp (no OOB)
        const float* xs = x + (size_t)gr * 512 + sc * 64;
        const int g = srow >> 4, l15w = srow & 15;
#pragma unroll
        for (int c2 = 0; c2 < 2; ++c2) {
            int kt = sc * 2 + c2;
            int base = ((kt * 4 + g) * 64 + l15w * 4) * 8;
#pragma unroll
            for (int q = 0; q < 2; ++q) {
                float4 f0 = *(const float4*)(xs + c2 * 32 + q * 16);
                float4 f1 = *(const float4*)(xs + c2 * 32 + q * 16 + 4);
                float4 f2 = *(const float4*)(xs + c2 * 32 + q * 16 + 8);
                float4 f3 = *(const float4*)(xs + c2 * 32 + q * 16 + 12);
                *(uint4*)&xImg[base + q * 16] =
                    make_uint4(pack2(f0.x, f0.y), pack2(f0.z, f0.w),
                               pack2(f1.x, f1.y), pack2(f1.z, f1.w));
                *(uint4*)&xImg[base + q * 16 + 8] =
                    make_uint4(pack2(f2.x, f2.y), pack2(f2.z, f2.w),
                               pack2(f3.x, f3.y), pack2(f3.z, f3.w));
            }
        }
    }
    __syncthreads();

    // ---- phase 1: barrier-free K-loop ----
    const ushort* bp0 = w1b + ((wid * 2 + 0) * 16 + l15) * 32 + lg * 8;
    const ushort* bp1 = w1b + ((wid * 2 + 1) * 16 + l15) * 32 + lg * 8;

    f32x4 acc[4][2];
#pragma unroll
    for (int g = 0; g < 4; ++g) {
        acc[g][0] = (f32x4)0.f;
        acc[g][1] = (f32x4)0.f;
    }

    bf16x8 Bb[2][2];
    Bb[0][0] = *(const bf16x8*)(bp0);
    Bb[0][1] = *(const bf16x8*)(bp1);
#pragma unroll
    for (int kt = 0; kt < 16; ++kt) {
        const int cur = kt & 1, nxt = cur ^ 1;
        if (kt < 15) {                                 // depth-1 B prefetch (L2)
            Bb[nxt][0] = *(const bf16x8*)(bp0 + (kt + 1) * 8192);
            Bb[nxt][1] = *(const bf16x8*)(bp1 + (kt + 1) * 8192);
        }
        bf16x8 A[4];
#pragma unroll
        for (int g = 0; g < 4; ++g)
            A[g] = *(const bf16x8*)&xImg[((kt * 4 + g) * 64 + l15 * 4 + lg) * 8];
#pragma unroll
        for (int g = 0; g < 4; ++g) {
            acc[g][0] = __builtin_amdgcn_mfma_f32_16x16x32_bf16(A[g], Bb[cur][0], acc[g][0], 0, 0, 0);
            acc[g][1] = __builtin_amdgcn_mfma_f32_16x16x32_bf16(A[g], Bb[cur][1], acc[g][1], 0, 0, 0);
        }
    }

    __syncthreads();                                   // x image dead below

    // ---- h1 = relu(acc+b1) -> bf16 -> LDS frag-linear image [0:32K) ----
    // wave wid's cols = ks block wid; rows g*16+lg*4+r
    ushort* h1l = xImg;
#pragma unroll
    for (int c = 0; c < 2; ++c) {
        int col = wid * 32 + c * 16 + l15;
        float bb = b1[col];
        int lgw = (col >> 3) & 3;
        int j = l15 & 7;
#pragma unroll
        for (int g = 0; g < 4; ++g) {
#pragma unroll
            for (int r = 0; r < 4; ++r) {
                float v = fmaxf(acc[g][c][r] + bb, 0.f);
                h1l[((wid * 4 + g) * 64 + (lg * 4 + r) * 4 + lgw) * 8 + j] = f2bf(v);
            }
        }
    }
    __syncthreads();

    if (wid >= 4) return;                              // no barriers below

    // ---- phase 2: wave wid -> rows wid*16..+15, all 64 cols, K=256 ----
    f32x4 acc2[4];
#pragma unroll
    for (int i = 0; i < 4; ++i) acc2[i] = (f32x4)0.f;
#pragma unroll
    for (int ks = 0; ks < 8; ++ks) {
        bf16x8 A = *(const bf16x8*)&h1l[((ks * 4 + wid) * 64 + l15 * 4 + lg) * 8];
#pragma unroll
        for (int nf = 0; nf < 4; ++nf) {
            size_t bo = (size_t)ks * 2048 + (nf * 16 + l15) * 32 + (lg << 3);
            bf16x8 Bh = *(const bf16x8*)(w2h + bo);
            bf16x8 Bl = *(const bf16x8*)(w2l + bo);
            acc2[nf] = __builtin_amdgcn_mfma_f32_16x16x32_bf16(A, Bh, acc2[nf], 0, 0, 0);
            acc2[nf] = __builtin_amdgcn_mfma_f32_16x16x32_bf16(A, Bl, acc2[nf], 0, 0, 0);
        }
    }

    // ---- epilogue ----
    int flag1 = flags[1];
    float a0c = acoef[0];
    float z[4][4];
#pragma unroll
    for (int nf = 0; nf < 4; ++nf) {
        float bb = b2[nf * 16 + l15];
#pragma unroll
        for (int r = 0; r < 4; ++r) z[nf][r] = acc2[nf][r] + bb;
    }
    if (!flag1) {
        // fused log_softmax: the 16 l15-lanes of this lg group share 4 rows
#pragma unroll
        for (int r = 0; r < 4; ++r) {
            int row = row0 + wid * 16 + lg * 4 + r;
            float mx = fmaxf(fmaxf(z[0][r], z[1][r]), fmaxf(z[2][r], z[3][r]));
#pragma unroll
            for (int off = 1; off < 16; off <<= 1) mx = fmaxf(mx, __shfl_xor(mx, off, 64));
            float s = expf(z[0][r] - mx) + expf(z[1][r] - mx)
                    + expf(z[2][r] - mx) + expf(z[3][r] - mx);
#pragma unroll
            for (int off = 1; off < 16; off <<= 1) s += __shfl_xor(s, off, 64);
            float lns = logf(s);
            if (row < N) {
#pragma unroll
                for (int nf = 0; nf < 4; ++nf)
                    out[(size_t)row * 64 + nf * 16 + l15] = z[nf][r] - mx - lns;
            }
        }
    } else {
#pragma unroll
        for (int nf = 0; nf < 4; ++nf) {
            int col = nf * 16 + l15;
#pragma unroll
            for (int r = 0; r < 4; ++r) {
                int row = row0 + wid * 16 + lg * 4 + r;
                if (row < N) {
                    size_t o = (size_t)row * 64 + col;
                    v0[o] = z[nf][r];
                    out[o] = a0c * z[nf][r];
                }
            }
        }
    }
}

// ---- all graph work in one cooperative kernel (active path only) ----------
__global__ __launch_bounds__(256) void graph_coop(
    const int* __restrict__ src, const int* __restrict__ dst, int E, int N,
    int* __restrict__ degs, int* __restrict__ degd, int* __restrict__ cursor,
    int* __restrict__ rowp, int* __restrict__ csrs, float* __restrict__ csrw,
    float* __restrict__ v0, float* __restrict__ v1, float* __restrict__ out,
    const float* __restrict__ acoef, const int* __restrict__ flags)
{
    __shared__ int sums[256];
    if (!flags[1]) return;                  // uniform early-out: no syncs occur
    cg::grid_group grid = cg::this_grid();
    int gtid = blockIdx.x * 256 + threadIdx.x;
    int gstr = gridDim.x * 256;

    for (int i = gtid; i < N; i += gstr) { degs[i] = 0; degd[i] = 0; cursor[i] = 0; }
    grid.sync();
    for (int e = gtid; e < E; e += gstr) {
        atomicAdd(&degs[src[e]], 1);
        atomicAdd(&degd[dst[e]], 1);
    }
    grid.sync();
    if (blockIdx.x == 0) {
        int tid = threadIdx.x;
        int chunk = (N + 255) / 256;
        int s0 = tid * chunk;
        int s1 = s0 + chunk; if (s1 > N) s1 = N; if (s0 > N) s0 = N;
        int s = 0;
        for (int i = s0; i < s1; ++i) s += degd[i];
        sums[tid] = s;
        __syncthreads();
        for (int off = 1; off < 256; off <<= 1) {
            int v = (tid >= off) ? sums[tid - off] : 0;
            __syncthreads();
            sums[tid] += v;
            __syncthreads();
        }
        int run = sums[tid] - s;
        for (int i = s0; i < s1; ++i) { rowp[i] = run; run += degd[i]; }
        if (tid == 255) rowp[N] = sums[255];
    }
    grid.sync();
    for (int e = gtid; e < E; e += gstr) {
        int s = src[e], d = dst[e];
        int dgs = degs[s], dgd = degs[d];
        float ws_ = (dgs > 0 ? rsqrtf((float)dgs) : 0.f)
                  * (dgd > 0 ? rsqrtf((float)dgd) : 0.f);
        int slot = rowp[d] + atomicAdd(&cursor[d], 1);
        csrs[slot] = s;
        csrw[slot] = ws_;
    }
    grid.sync();
    const float* va = v0;
    float* vb = v1;
    int lane = threadIdx.x & 63;
    int grpbase = lane & 48;
    for (int j = 1; j <= KORD; ++j) {
        if (!flags[j]) break;               // uniform
        float aj = acoef[j];
        for (int idx = gtid; idx < N * 16; idx += gstr) {
            int n = idx >> 4;
            int q = idx & 15;
            int beg = rowp[n], end = rowp[n + 1];
            float4 acc = make_float4(0.f, 0.f, 0.f, 0.f);
            for (int base = beg; base < end; base += 16) {
                int s = 0; float wvv = 0.f;
                int ii = base + q;
                if (ii < end) { s = csrs[ii]; wvv = csrw[ii]; }
                int m = end - base; if (m > 16) m = 16;
                for (int u = 0; u < m; ++u) {
                    int ss = __shfl(s, grpbase + u, 64);
                    float ww = __shfl(wvv, grpbase + u, 64);
                    float4 vv = *(const float4*)(va + ((long)ss << 6) + (q << 2));
                    acc.x += ww * vv.x; acc.y += ww * vv.y;
                    acc.z += ww * vv.z; acc.w += ww * vv.w;
                }
            }
            long o = ((long)n << 6) + (q << 2);
            *(float4*)(vb + o) = acc;
            float4 ov = *(const float4*)(out + o);
            ov.x += aj * acc.x; ov.y += aj * acc.y;
            ov.z += aj * acc.z; ov.w += aj * acc.w;
            *(float4*)(out + o) = ov;
        }
        grid.sync();
        float* tsw = vb; vb = (float*)va; va = tsw;
    }
    for (int idx = gtid; idx < N * 64; idx += gstr) {
        int n = idx >> 6;
        int c = idx & 63;
        float v = out[(long)n * 64 + c];
        float mx = v;
#pragma unroll
        for (int off = 32; off; off >>= 1) mx = fmaxf(mx, __shfl_xor(mx, off, 64));
        float e = expf(v - mx);
        float s = e;
#pragma unroll
        for (int off = 32; off; off >>= 1) s += __shfl_xor(s, off, 64);
        out[(long)n * 64 + c] = v - mx - logf(s);
    }
}

extern "C" void kernel_launch(void* const* d_in, const int* in_sizes, int n_in,
                              void* d_out, int out_size, void* d_ws, size_t ws_size,
                              hipStream_t stream)
{
    const float* x    = (const float*)d_in[0];
    const int*   ei   = (const int*)d_in[1];
    const float* W1   = (const float*)d_in[2];
    const float* b1   = (const float*)d_in[3];
    const float* W2   = (const float*)d_in[4];
    const float* b2   = (const float*)d_in[5];
    const float* temp = (const float*)d_in[6];

    int N = in_sizes[0] / 512;
    int E = in_sizes[1] / 2;
    const int* src = ei;
    const int* dst = ei + E;
    float* out = (float*)d_out;

    char* w = (char*)d_ws;
    auto alloc = [&](size_t bytes) {
        char* p = w;
        w += (bytes + 255) & ~(size_t)255;
        return p;
    };
    float* acoef  = (float*)alloc(64);
    int*   flags  = (int*)alloc(64);
    int*   degs   = (int*)alloc((size_t)N * 4);
    int*   degd   = (int*)alloc((size_t)N * 4);
    int*   cursor = (int*)alloc((size_t)N * 4);
    int*   rowp   = (int*)alloc((size_t)(N + 1) * 4);
    int*   csrs   = (int*)alloc((size_t)E * 4);
    float* csrw   = (float*)alloc((size_t)E * 4);
    ushort* w1b   = (ushort*)alloc(512 * 256 * 2);
    ushort* w2h   = (ushort*)alloc(256 * 64 * 2);
    ushort* w2l   = (ushort*)alloc(256 * 64 * 2);
    float* v0     = (float*)alloc((size_t)N * 64 * 4);
    float* v1     = (float*)alloc((size_t)N * 64 * 4);

    prep_all<<<576, 256, 0, stream>>>(temp, W1, W2, acoef, flags, w1b, w2h, w2l);

    int ntiles = (N + 63) / 64;
    mlp_kernel<<<ntiles, 512, 0, stream>>>(x, w1b, w2h, w2l, b1, b2, v0, out,
                                           acoef, flags, N);

    int Ei = E, Ni = N;
    void* cargs[] = {
        (void*)&src, (void*)&dst, (void*)&Ei, (void*)&Ni,
        (void*)&degs, (void*)&degd, (void*)&cursor, (void*)&rowp,
        (void*)&csrs, (void*)&csrw, (void*)&v0, (void*)&v1, (void*)&out,
        (void*)&acoef, (void*)&flags
    };
    hipLaunchCooperativeKernel((void*)graph_coop, dim3(1024), dim3(256),
                               cargs, 0, stream);
}